// Round 4
// baseline (66.431 us; speedup 1.0000x reference)
//
#include <hip/hip_runtime.h>
#include <stdint.h>

#define NRAYS 262144
#define DT (1.0f/99.0f)
#define RPT 4                 // rays per thread
#define NTHREADS (NRAYS / RPT)

// ---------- exact-order helpers (bit-exact vs numpy reference) ----------

struct SampleE { float itv, px, py, pz, v; };

// Sample k of the ray sampler, exact reference op order.
// numpy linspace endpoint: t[99] = 1.0 exactly.
__device__ __forceinline__ SampleE eval_k(int k, float smin, float diff,
                                          float ox, float oy, float oz,
                                          float dx, float dy, float dz) {
#pragma clang fp contract(off)
    float t = (k == 99) ? 1.0f : (float)k * DT;
    float itv = smin + t * diff;
    float px = ox + dx * itv;
    float py = oy + dy * itv;
    float pz = oz + dz * itv;
    float v = ((px * px + py * py) + pz * pz) + 1e-12f;
    SampleE e; e.itv = itv; e.px = px; e.py = py; e.pz = pz; e.v = v;
    return e;
}

// ---------- fast-path helpers ----------

__device__ __forceinline__ float fast_div(float n, float d) {
    float r = __builtin_amdgcn_rcpf(d);
    r = r * (2.0f - d * r);          // 1 Newton step
    return n * r;
}

// ============================================================
// 4-rays-per-thread kernel: intersect + MIRRORED sphere tracing +
// analytic sampler. Math per ray identical to the 1-ray version
// (mirror symmetry + closed-form secant root, see prior rounds);
// this version adds 4-way ILP on the dependent sqrt chain, 4x fewer
// per-wave fixed costs, and float4-clean loads/stores.
// ============================================================
__global__ __launch_bounds__(256) void raytrace_kernel(
    const float* __restrict__ cam,
    const float* __restrict__ dirs,
    const void* __restrict__ maskp,
    float* __restrict__ out)
{
#pragma clang fp contract(off)
    const int t = blockIdx.x * 256 + threadIdx.x;

    // ---- object_mask storage probe (int32 / float32 / byte-packed bool) ----
    // All 64 lanes active here (before any divergence) so ballot is safe.
    const int* mi = (const int*)maskp;
    const int lane = threadIdx.x & 63;
    bool clean = true;
#pragma unroll
    for (int k = 0; k < 4; ++k) {
        int v = mi[lane + 64 * k];
        clean = clean && (v == 0 || v == 1 || v == 0x3F800000);
    }
    unsigned long long bal = __ballot(clean);
    const bool byte_packed = (bal != 0xFFFFFFFFFFFFFFFFull);

    bool obj[RPT];
    if (byte_packed) {
        uchar4 m4 = ((const uchar4*)maskp)[t];
        obj[0] = m4.x != 0; obj[1] = m4.y != 0;
        obj[2] = m4.z != 0; obj[3] = m4.w != 0;
    } else {
        int4 m4 = ((const int4*)maskp)[t];
        obj[0] = m4.x != 0; obj[1] = m4.y != 0;
        obj[2] = m4.z != 0; obj[3] = m4.w != 0;
    }

    // ---- load 4 rays, float4-vectorized ([N][3] layout: 12 floats/thread) --
    const float4* c4 = (const float4*)cam;
    const float4* d4 = (const float4*)dirs;
    float4 cA = c4[3 * t], cB = c4[3 * t + 1], cC = c4[3 * t + 2];
    float4 dA = d4[3 * t], dB = d4[3 * t + 1], dC = d4[3 * t + 2];

    float oxr[RPT] = { cA.x, cA.w, cB.z, cC.y };
    float oyr[RPT] = { cA.y, cB.x, cB.w, cC.z };
    float ozr[RPT] = { cA.z, cB.y, cC.x, cC.w };
    float dxr[RPT] = { dA.x, dA.w, dB.z, dC.y };
    float dyr[RPT] = { dA.y, dB.x, dB.w, dC.z };
    float dzr[RPT] = { dA.z, dB.y, dC.x, dC.w };

    // ---- per-ray state (all statically indexed via full unroll) ----
    float a[RPT], ob[RPT], oo[RPT], b2[RPT], c2[RPT];
    float acc_s[RPT], acc_e[RPT], next_s[RPT];
    bool unf[RPT];

    #define PSDF(r, tt) (__builtin_amdgcn_sqrtf( \
        fmaf(fmaf(a[r], (tt), b2[r]), (tt), c2[r])) - 0.5f)

#pragma unroll
    for (int r = 0; r < RPT; ++r) {
        const float ox = oxr[r], oy = oyr[r], oz = ozr[r];
        const float dx = dxr[r], dy = dyr[r], dz = dzr[r];
        // _sphere_intersect (exact)
        a[r]  = dx * dx + dy * dy + dz * dz;
        ob[r] = ox * dx + oy * dy + oz * dz;
        float bq = 2.0f * ob[r];
        oo[r] = ox * ox + oy * oy + oz * oz;
        float cq = oo[r] - 1.0f;
        float under = bq * bq - (4.0f * a[r]) * cq;
        bool mk = under > 0.0f;
        float sq = __fsqrt_rn(fmaxf(under, 0.0f));
        float nearv = fmaxf(mk ? (-sq - bq) * 0.5f : 0.0f, 0.01f);
        float farv  = fmaxf(mk ? ( sq - bq) * 0.5f : 0.0f, 0.01f);
        b2[r] = ob[r] + ob[r];
        c2[r] = oo[r] + 1e-12f;
        unf[r] = mk;
        acc_s[r] = nearv;
        acc_e[r] = farv;
        next_s[r] = mk ? PSDF(r, nearv) : 0.0f;
    }

    // ---- mirrored sphere tracing: 4 independent chains interleaved ----
    for (int it = 0; it < 10; ++it) {
#pragma unroll
        for (int r = 0; r < RPT; ++r) {
            float cs = unf[r] ? next_s[r] : 0.0f;
            cs = (cs <= 5e-5f) ? 0.0f : cs;
            unf[r] = unf[r] && (cs > 5e-5f);

            acc_s[r] = acc_s[r] + cs;
            acc_e[r] = acc_e[r] - cs;           // mirror: ce == cs
            next_s[r] = unf[r] ? PSDF(r, acc_s[r]) : 0.0f;

            bool nps = next_s[r] < 0.0f;
            // overshoot ~never happens (exact sphere SDF); execz-skip branch
            if (nps) {
                float as2 = acc_s[r] - 0.5f * cs;
                float ae2 = acc_e[r] + 0.5f * cs;
                float ns2 = PSDF(r, as2);
                acc_s[r] = as2;
                acc_e[r] = ae2;
                next_s[r] = ns2;
            }

            unf[r] = unf[r] && (acc_s[r] < acc_e[r]);
        }
        // Converged state is a fixpoint: skipping the rest is exact.
        if (!__any(unf[0] || unf[1] || unf[2] || unf[3])) break;
    }

    // ---- outputs per ray ----
    float OX[RPT], OY[RPT], OZ[RPT], ONET[RPT], ODIST[RPT];

#pragma unroll
    for (int r = 0; r < RPT; ++r) {
        const float ox = oxr[r], oy = oyr[r], oz = ozr[r];
        const float dx = dxr[r], dy = dyr[r], dz = dzr[r];

        // trailing _upd_mask (only s-side survives; unf_e == unf_s)
        bool sm = unf[r] && (next_s[r] > 5e-5f);

        // default outputs (converged rays): exact reference op order
        OX[r] = ox + acc_s[r] * dx;
        OY[r] = oy + acc_s[r] * dy;
        OZ[r] = oz + acc_s[r] * dz;
        ONET[r] = (acc_s[r] < acc_e[r]) ? 1.0f : 0.0f;
        ODIST[r] = acc_s[r];

        if (sm) {
            const float smin = acc_s[r], smax = acc_e[r];
            const float diff = smax - smin;
            const float denk = diff * DT;

            // vertex window: discrete argmin + hasNeg, exact FP order at
            // the 3 candidate samples {kv-1, kv, kv+1} (clamped; +-1 margin
            // absorbs the rcp error; duplicates at edges don't shift argmin)
            float tstar = fast_div(-ob[r], a[r]);           // parabola vertex
            float kf = (diff > 0.0f) ? fast_div(tstar - smin, denk) : 0.0f;
            kf = fminf(fmaxf(kf, 0.0f), 99.0f);
            int kv = (int)floorf(kf + 0.5f);
            int km1 = (kv > 0)  ? kv - 1 : 0;
            int kp1 = (kv < 99) ? kv + 1 : 99;

            float v0 = eval_k(km1, smin, diff, ox, oy, oz, dx, dy, dz).v;
            float v1 = eval_k(kv,  smin, diff, ox, oy, oz, dx, dy, dz).v;
            float v2 = eval_k(kp1, smin, diff, ox, oy, oz, dx, dy, dz).v;
            int omin = km1; float vmin = v0;
            if (v1 < vmin) { vmin = v1; omin = kv; }
            if (v2 < vmin) { vmin = v2; omin = kp1; }
            const bool hasNeg = vmin < 0.25f;               // == net_surface

            if (obj[r] && hasNeg) {
                // sec ray: closed-form surface root (secant fixpoint)
                float cs25 = (oo[r] + 1e-12f) - 0.25f;
                float disc = ob[r] * ob[r] - a[r] * cs25;
                float r0 = fast_div(-ob[r] - __fsqrt_rn(fmaxf(disc, 0.0f)), a[r]);
                OX[r] = ox + r0 * dx;
                OY[r] = oy + r0 * dy;
                OZ[r] = oz + r0 * dz;
                ODIST[r] = r0;
                ONET[r] = 1.0f;
            } else {
                // p_out ray: argmin sample
                SampleE eO = eval_k(omin, smin, diff, ox, oy, oz, dx, dy, dz);
                OX[r] = eO.px; OY[r] = eO.py; OZ[r] = eO.pz;
                ODIST[r] = eO.itv;
                ONET[r] = hasNeg ? 1.0f : 0.0f;
            }
        }
    }

    // ---- float4-vectorized stores ----
    float4* o4 = (float4*)out;
    o4[3 * t]     = make_float4(OX[0], OY[0], OZ[0], OX[1]);
    o4[3 * t + 1] = make_float4(OY[1], OZ[1], OX[2], OY[2]);
    o4[3 * t + 2] = make_float4(OZ[2], OX[3], OY[3], OZ[3]);
    o4[(3 * NRAYS) / 4 + t] = make_float4(ONET[0], ONET[1], ONET[2], ONET[3]);
    o4[(4 * NRAYS) / 4 + t] = make_float4(ODIST[0], ODIST[1], ODIST[2], ODIST[3]);
}

extern "C" void kernel_launch(void* const* d_in, const int* in_sizes, int n_in,
                              void* d_out, int out_size, void* d_ws, size_t ws_size,
                              hipStream_t stream) {
    const float* cam  = (const float*)d_in[0];
    const float* dirs = (const float*)d_in[1];
    const void* maskp = d_in[2];
    float* out = (float*)d_out;
    dim3 grid(NTHREADS / 256), block(256);
    raytrace_kernel<<<grid, block, 0, stream>>>(cam, dirs, maskp, out);
}

// Round 5
// 64.101 us; speedup vs baseline: 1.0364x; 1.0364x over previous
//
#include <hip/hip_runtime.h>
#include <stdint.h>

#define NRAYS 262144
#define DT (1.0f/99.0f)

// ---------- exact-order helpers (bit-exact vs numpy reference) ----------

struct SampleE { float itv, px, py, pz, v; };

// Sample k of the ray sampler, exact reference op order.
// numpy linspace endpoint: t[99] = 1.0 exactly.
__device__ __forceinline__ SampleE eval_k(int k, float smin, float diff,
                                          float ox, float oy, float oz,
                                          float dx, float dy, float dz) {
#pragma clang fp contract(off)
    float t = (k == 99) ? 1.0f : (float)k * DT;
    float itv = smin + t * diff;
    float px = ox + dx * itv;
    float py = oy + dy * itv;
    float pz = oz + dz * itv;
    float v = ((px * px + py * py) + pz * pz) + 1e-12f;
    SampleE e; e.itv = itv; e.px = px; e.py = py; e.pz = pz; e.v = v;
    return e;
}

// ---------- fast-path helpers ----------

__device__ __forceinline__ float fast_div(float n, float d) {
    float r = __builtin_amdgcn_rcpf(d);
    r = r * (2.0f - d * r);          // 1 Newton step
    return n * r;
}

// ============================================================
// Monolithic kernel: intersect + MIRRORED sphere tracing + analytic sampler.
// (Best-measured structure: 1 ray/thread, 16 waves/CU. The 4-ray/thread
// ILP variant regressed: occupancy 4x down + divergence footprint 4x up.)
//
// Mirror symmetry: with |d| ~= 1 the reference's s-side and e-side tracing
// iterations are exact mirror images about t_c = -o.d:
//   u_s0 = t_c - near == far - t_c = u_e0   (same sq in _sphere_intersect)
//   u_{n+1} = u_n - sqrt(u_n^2 + b^2) + r   (identical map both sides)
// => ce == cs, unf_e == unf_s, np_e == np_s every iteration, up to ~1e-7
// fp asymmetry (a != 1 by ~1e-7) -- the same error class as the PSDF
// polynomial substitution. So trace ONE side; acc_e = far - sum(cs) keeps
// mask=0 rays exact and preserves the crossing test acc_s < acc_e.
//
// Sampler dead-code analysis (vs reference): within smask,
//   p_out = !(obj && hasNeg), sec = obj && hasNeg,
// so every smask ray outputs either the argmin sample (omin) or the secant
// root; the secant converges to the root of
//   a z^2 + 2 ob z + (oo + 1e-12 - 0.25) = 0
// independent of bracket -> closed form r0 replaces search+secant.
// ============================================================
__global__ __launch_bounds__(256) void raytrace_kernel(
    const float* __restrict__ cam,
    const float* __restrict__ dirs,
    const void* __restrict__ maskp,
    float* __restrict__ out)
{
#pragma clang fp contract(off)
    const int i = blockIdx.x * 256 + threadIdx.x;

    // ---- object_mask storage probe (int32 / float32 / byte-packed bool) ----
    // All 64 lanes active here (before any divergence) so ballot is safe.
    const int* mi = (const int*)maskp;
    const int lane = threadIdx.x & 63;
    bool clean = true;
#pragma unroll
    for (int k = 0; k < 4; ++k) {
        int v = mi[lane + 64 * k];
        clean = clean && (v == 0 || v == 1 || v == 0x3F800000);
    }
    unsigned long long bal = __ballot(clean);
    const bool byte_packed = (bal != 0xFFFFFFFFFFFFFFFFull);
    const bool obj = byte_packed ? (((const unsigned char*)maskp)[i] != 0)
                                 : (mi[i] != 0);

    // ---- load ray ----
    const float ox = cam[3 * i], oy = cam[3 * i + 1], oz = cam[3 * i + 2];
    const float dx = dirs[3 * i], dy = dirs[3 * i + 1], dz = dirs[3 * i + 2];

    // ---- _sphere_intersect (exact) ----
    float a  = dx * dx + dy * dy + dz * dz;
    float ob = ox * dx + oy * dy + oz * dz;
    float b  = 2.0f * ob;
    float oo = ox * ox + oy * oy + oz * oz;
    float c  = oo - 1.0f;
    float under = b * b - (4.0f * a) * c;
    const bool mask = under > 0.0f;
    float sq = __fsqrt_rn(fmaxf(under, 0.0f));
    float nearv = fmaxf(mask ? (-sq - b) * 0.5f : 0.0f, 0.01f);
    float farv  = fmaxf(mask ? ( sq - b) * 0.5f : 0.0f, 0.01f);

    // ---- mirrored sphere tracing: one side, one sqrt per iteration ----
    const float b2 = ob + ob;
    const float c2 = oo + 1e-12f;
    #define PSDF(t) (__builtin_amdgcn_sqrtf(fmaf(fmaf(a,(t),b2),(t),c2)) - 0.5f)

    bool unf = mask;
    float acc_s = nearv, acc_e = farv;
    float next_s = unf ? PSDF(nearv) : 0.0f;

    for (int it = 0; it < 10; ++it) {
        float cs = unf ? next_s : 0.0f;
        cs = (cs <= 5e-5f) ? 0.0f : cs;
        unf = unf && (cs > 5e-5f);

        acc_s = acc_s + cs;
        acc_e = acc_e - cs;                 // mirror: ce == cs
        next_s = unf ? PSDF(acc_s) : 0.0f;

        bool nps = next_s < 0.0f;
        // Exact sphere SDF essentially never oversteps; gate the line-search
        // transcendental behind a wave-level any.
        if (__any(nps)) {
            float acc_s2 = acc_s - 0.5f * cs;
            float acc_e2 = acc_e + 0.5f * cs;   // mirror of e-side line step
            float next_s2 = PSDF(acc_s2);
            acc_s  = nps ? acc_s2  : acc_s;
            acc_e  = nps ? acc_e2  : acc_e;
            next_s = nps ? next_s2 : next_s;
        }

        bool ok = acc_s < acc_e;
        unf = unf && ok;

        // Converged state is a fixpoint: skipping the rest is exact.
        if (!__any(unf)) break;
    }
    // trailing _upd_mask (only unf_s survives into outputs; unf_e == unf_s)
    unf = unf && (next_s > 5e-5f);

    // Final curr_pts in exact reference op order.
    const float csx = ox + acc_s * dx;
    const float csy = oy + acc_s * dy;
    const float csz = oz + acc_s * dz;

    const bool net0 = (acc_s < acc_e);
    const bool smask = unf;
    const float smin = smask ? acc_s : 0.0f;
    const float smax = smask ? acc_e : 0.0f;
    const float diff = smax - smin;
    const float denk = diff * DT;

    // default outputs (converged rays)
    float outx = csx, outy = csy, outz = csz;
    float outnet = net0 ? 1.0f : 0.0f;
    float outdist = acc_s;

    if (__any(smask)) {
        // ---- vertex window: global discrete argmin + hasNeg, exact FP order --
        // v(k) is a positive parabola in k; the discrete min lies in
        // {kv-1, kv, kv+1} around the (fast-div) vertex estimate; the +-1
        // margin absorbs the rcp error. eval_k matches reference rounding
        // exactly, so hasNeg/omin are exact (mod argmin ties at the window
        // edge, O(1e-2) output shift, inside the accepted band).
        float tstar = fast_div(-ob, a);             // parabola vertex
        float kf = (diff > 0.0f) ? fast_div(tstar - smin, denk) : 0.0f;
        kf = fminf(fmaxf(kf, 0.0f), 99.0f);
        int kv = (int)floorf(kf + 0.5f);
        int w0 = kv - 1; if (w0 < 0) w0 = 0;
        int w1 = kv + 1; if (w1 > 99) w1 = 99;

        int omin = w0; float vmin = 3.4e38f;
        for (int k = w0; k <= w1; ++k) {
            float vk = eval_k(k, smin, diff, ox, oy, oz, dx, dy, dz).v;
            if (vk < vmin) { vmin = vk; omin = k; }
        }
        const bool hasNeg = vmin < 0.25f;           // == net_surface

        if (smask) {
            if (obj && hasNeg) {
                // sec ray: closed-form surface root (secant fixpoint)
                float cs25 = (oo + 1e-12f) - 0.25f;
                float disc = ob * ob - a * cs25;
                float r0 = fast_div(-ob - __fsqrt_rn(fmaxf(disc, 0.0f)), a);
                outx = ox + r0 * dx;
                outy = oy + r0 * dy;
                outz = oz + r0 * dz;
                outdist = r0;
                outnet = 1.0f;                      // hasNeg
            } else {
                // p_out ray: argmin sample
                SampleE eO = eval_k(omin, smin, diff, ox, oy, oz, dx, dy, dz);
                outx = eO.px; outy = eO.py; outz = eO.pz;
                outdist = eO.itv;
                outnet = hasNeg ? 1.0f : 0.0f;
            }
        }
    }

    // ---- store ----
    out[3 * i]     = outx;
    out[3 * i + 1] = outy;
    out[3 * i + 2] = outz;
    out[3 * NRAYS + i] = outnet;
    out[4 * NRAYS + i] = outdist;
}

extern "C" void kernel_launch(void* const* d_in, const int* in_sizes, int n_in,
                              void* d_out, int out_size, void* d_ws, size_t ws_size,
                              hipStream_t stream) {
    const float* cam  = (const float*)d_in[0];
    const float* dirs = (const float*)d_in[1];
    const void* maskp = d_in[2];
    float* out = (float*)d_out;
    dim3 grid(NRAYS / 256), block(256);
    raytrace_kernel<<<grid, block, 0, stream>>>(cam, dirs, maskp, out);
}